// Round 1
// baseline (151.219 us; speedup 1.0000x reference)
//
#include <hip/hip_runtime.h>

// SIR recurrence, steps=200000, output = trajectory [steps-1, 3] float32.
//
// Structure: strictly sequential nonlinear scan (S*I term) -> one-thread scan,
// BUT float32 SIR dynamics hit a bitwise fixed point once I underflows /
// drops below ulp(S). After new==old bitwise, all later rows are identical,
// so: scan until fixed point (writing rows), then parallel-fill the tail.
// Exact w.r.t. the full sequential scan (deterministic step function).

struct FixInfo {
    int   t;        // first row index NOT written by the scan kernel
    float S, I, R;  // state to replicate into rows [t, n)
};

__global__ void sir_scan(const float* __restrict__ x,
                         const float* __restrict__ bw,
                         const float* __restrict__ gw,
                         float* __restrict__ out,
                         int n, FixInfo* __restrict__ fi) {
    if (threadIdx.x != 0) return;
    float S = x[0], I = x[1], R = x[2];
    // pop = x.sum() in numpy order: (x0 + x1) + x2
    float pop = __fadd_rn(__fadd_rn(S, I), R);
    float b = bw[0], g = gw[0];

    int t = 0;
    while (t < n) {
        // inf = (b*S)*I  (python left-assoc), rec = g*I, no FMA contraction
        float inf = __fmul_rn(__fmul_rn(b, S), I);
        float rec = __fmul_rn(g, I);
        float nS = __fsub_rn(S, inf);
        float nI = __fsub_rn(__fadd_rn(I, inf), rec);
        float nR = __fadd_rn(R, rec);
        // clip(v, 0, pop) = min(max(v, 0), pop)
        nS = fminf(fmaxf(nS, 0.0f), pop);
        nI = fminf(fmaxf(nI, 0.0f), pop);
        nR = fminf(fmaxf(nR, 0.0f), pop);
        bool fixed = (nS == S) && (nI == I) && (nR == R);
        S = nS; I = nI; R = nR;
        out[3 * t + 0] = S;
        out[3 * t + 1] = I;
        out[3 * t + 2] = R;
        ++t;
        if (fixed) break;  // f(state)==state bitwise => all later rows identical
    }
    fi->t = t; fi->S = S; fi->I = I; fi->R = R;
}

__global__ void sir_fill(float* __restrict__ out, int n,
                         const FixInfo* __restrict__ fi) {
    int row = blockIdx.x * blockDim.x + threadIdx.x;
    if (row >= n) return;
    int t0 = fi->t;
    if (row >= t0) {
        float S = fi->S, I = fi->I, R = fi->R;
        out[3 * row + 0] = S;
        out[3 * row + 1] = I;
        out[3 * row + 2] = R;
    }
}

extern "C" void kernel_launch(void* const* d_in, const int* in_sizes, int n_in,
                              void* d_out, int out_size, void* d_ws, size_t ws_size,
                              hipStream_t stream) {
    const float* x  = (const float*)d_in[0];
    const float* bw = (const float*)d_in[1];
    const float* gw = (const float*)d_in[2];
    float* out = (float*)d_out;
    int n = out_size / 3;  // steps - 1 rows

    FixInfo* fi = (FixInfo*)d_ws;

    sir_scan<<<1, 64, 0, stream>>>(x, bw, gw, out, n, fi);

    int blocks = (n + 255) / 256;
    sir_fill<<<blocks, 256, 0, stream>>>(out, n, fi);
}

// Round 2
// 86.798 us; speedup vs baseline: 1.7422x; 1.7422x over previous
//
#include <hip/hip_runtime.h>

// SIR recurrence, steps=200000, output = trajectory [steps-1, 3] float32.
//
// R1 -> R2: scan loop slimmed. Clamps dropped (mathematically no-ops: sum
// conserved, all compartments stay in [0,pop] up to 1-ulp rounding; threshold
// is 4.5e-2). FMA-form update, unroll x8, fixpoint check once per octet
// (consecutive-state equality at octet end == exact fixpoint test, since the
// step is a deterministic function of state alone).

struct FixInfo {
    int   t;        // first row index NOT written by the scan kernel
    float S, I, R;  // state to replicate into rows [t, n)
};

__global__ void sir_scan(const float* __restrict__ x,
                         const float* __restrict__ bw,
                         const float* __restrict__ gw,
                         float* __restrict__ out,
                         int n, FixInfo* __restrict__ fi) {
    if (threadIdx.x != 0) return;
    float S = x[0], I = x[1], R = x[2];
    float b = bw[0], g = gw[0];
    float cg = 1.0f - g;

    int t = 0;
    bool fixed = false;
    float* p = out;

    // main loop: octets of 8 steps, one fixpoint check per octet
    while (t + 8 <= n) {
        float pS = S, pI = I, pR = R;  // state one step before octet end
#pragma unroll
        for (int k = 0; k < 8; ++k) {
            pS = S; pI = I; pR = R;
            float f  = fmaf(b, S, cg);       // 1 + b*S - g
            float t1 = b * I;
            float nS = fmaf(-t1, S, S);      // S - b*S*I
            float nI = I * f;                // I*(1 + b*S - g)
            float nR = fmaf(g, I, R);        // R + g*I
            S = nS; I = nI; R = nR;
            p[0] = S; p[1] = I; p[2] = R;
            p += 3;
        }
        t += 8;
        if (S == pS && I == pI && R == pR) { fixed = true; break; }
    }

    // tail (only if we never fixed): at most 7 steps
    if (!fixed) {
        while (t < n) {
            float f  = fmaf(b, S, cg);
            float t1 = b * I;
            float nS = fmaf(-t1, S, S);
            float nI = I * f;
            float nR = fmaf(g, I, R);
            S = nS; I = nI; R = nR;
            p[0] = S; p[1] = I; p[2] = R;
            p += 3;
            ++t;
        }
    }

    fi->t = t; fi->S = S; fi->I = I; fi->R = R;
}

__global__ void sir_fill(float* __restrict__ out, int n,
                         const FixInfo* __restrict__ fi) {
    int row = blockIdx.x * blockDim.x + threadIdx.x;
    if (row >= n) return;
    int t0 = fi->t;
    if (row >= t0) {
        float S = fi->S, I = fi->I, R = fi->R;
        out[3 * row + 0] = S;
        out[3 * row + 1] = I;
        out[3 * row + 2] = R;
    }
}

extern "C" void kernel_launch(void* const* d_in, const int* in_sizes, int n_in,
                              void* d_out, int out_size, void* d_ws, size_t ws_size,
                              hipStream_t stream) {
    const float* x  = (const float*)d_in[0];
    const float* bw = (const float*)d_in[1];
    const float* gw = (const float*)d_in[2];
    float* out = (float*)d_out;
    int n = out_size / 3;  // steps - 1 rows

    FixInfo* fi = (FixInfo*)d_ws;

    sir_scan<<<1, 64, 0, stream>>>(x, bw, gw, out, n, fi);

    int blocks = (n + 255) / 256;
    sir_fill<<<blocks, 256, 0, stream>>>(out, n, fi);
}